// Round 3
// baseline (717.313 us; speedup 1.0000x reference)
//
#include <hip/hip_runtime.h>
#include <hip/hip_bf16.h>
#include <math.h>

typedef __hip_bfloat16 bf16;

__device__ __forceinline__ float elu_f(float x){ return x > 0.f ? x : expm1f(x); }

// ---------- dtype detection ----------
// flags[0] = 1 if edge_index is int64 (odd 32-bit words all zero)
// flags[1] = 1 if float arrays are bf16 (low-half exponent field clusters like normal(0,1))
__global__ void detect_kernel(const unsigned* __restrict__ ei_u, int twoE_words,
                              const unsigned* __restrict__ x_u, int min_xwords,
                              int* __restrict__ flags){
    __shared__ int sd[256];
    __shared__ int sc[256];
    int tid = threadIdx.x;
    int acc = 0;
    for (int i = tid; i < 65536; i += 256){
        int idx = 2*i + 1;
        if (idx < twoE_words) acc |= (int)ei_u[idx];
    }
    int cnt = 0;
    for (int i = tid; i < 4096; i += 256){
        int w = i * 512 + 7;                 // strided sample, max < 2.1M words
        if (w < min_xwords){
            unsigned e = (x_u[w] >> 7) & 0xFFu;   // low-half bf16 exponent field
            cnt += (e >= 96u && e <= 160u) ? 1 : 0;
        }
    }
    sd[tid] = acc; sc[tid] = cnt;
    __syncthreads();
    #pragma unroll
    for (int off = 128; off > 0; off >>= 1){
        if (tid < off){ sd[tid] |= sd[tid+off]; sc[tid] += sc[tid+off]; }
        __syncthreads();
    }
    if (tid == 0){
        flags[0] = (sd[0] == 0) ? 1 : 0;
        flags[1] = (sc[0]*2 > 4096) ? 1 : 0;
    }
}

__device__ __forceinline__ int load_src(const int* ei, int e, int E, int is64){
    return is64 ? ei[2*e] : ei[e];
}
__device__ __forceinline__ int load_dst(const int* ei, int e, int E, int is64){
    return is64 ? ei[2*(E + e)] : ei[E + e];
}
// branched scalar load of a "float-ish" array
__device__ __forceinline__ float loadf(const void* base, size_t idx, int isbf){
    return isbf ? __bfloat162float(((const bf16*)base)[idx]) : ((const float*)base)[idx];
}

// ---------- CSR build ----------
__global__ void count_kernel(const int* __restrict__ ei, const int* __restrict__ flags,
                             int* __restrict__ counts, int E, int N){
    int e = blockIdx.x*256 + threadIdx.x;
    if (e < E){
        int d = load_dst(ei, e, E, flags[0]);
        if ((unsigned)d < (unsigned)N) atomicAdd(&counts[d], 1);
    }
}

__global__ void dinv_kernel(const int* __restrict__ counts, float* __restrict__ dinv, int N){
    int n = blockIdx.x*256 + threadIdx.x;
    if (n < N){
        double d = (double)(counts[n] + 1);
        if (d < 1.0) d = 1.0;
        dinv[n] = (float)(1.0 / sqrt(d));
    }
}

__global__ void partial_kernel(const int* __restrict__ counts, int* __restrict__ partial, int N){
    __shared__ int sd[256];
    int tid = threadIdx.x;
    int i = blockIdx.x*256 + tid;
    sd[tid] = (i < N) ? counts[i] : 0;
    __syncthreads();
    #pragma unroll
    for (int off = 128; off > 0; off >>= 1){
        if (tid < off) sd[tid] += sd[tid+off];
        __syncthreads();
    }
    if (tid == 0) partial[blockIdx.x] = sd[0];
}

__global__ void scanp_kernel(const int* __restrict__ partial, int* __restrict__ blockoff, int nb){
    __shared__ int sd[256];
    int tid = threadIdx.x;
    int v = (tid < nb) ? partial[tid] : 0;
    sd[tid] = v;
    __syncthreads();
    #pragma unroll
    for (int off = 1; off < 256; off <<= 1){
        int t = (tid >= off) ? sd[tid-off] : 0;
        __syncthreads();
        sd[tid] += t;
        __syncthreads();
    }
    if (tid < nb) blockoff[tid] = sd[tid] - v;
}

__global__ void offsets_kernel(const int* __restrict__ counts, const int* __restrict__ blockoff,
                               int* __restrict__ offsets, int* __restrict__ cursor, int N){
    __shared__ int sd[256];
    int tid = threadIdx.x;
    int i = blockIdx.x*256 + tid;
    int v = (i < N) ? counts[i] : 0;
    sd[tid] = v;
    __syncthreads();
    #pragma unroll
    for (int off = 1; off < 256; off <<= 1){
        int t = (tid >= off) ? sd[tid-off] : 0;
        __syncthreads();
        sd[tid] += t;
        __syncthreads();
    }
    if (i < N){
        int o = blockoff[blockIdx.x] + sd[tid] - v;
        offsets[i] = o;
        cursor[i]  = o;
    }
}

__global__ void scatter_kernel(const int* __restrict__ ei, const int* __restrict__ flags,
                               int* __restrict__ cursor, int* __restrict__ csr, int E, int N){
    int e = blockIdx.x*256 + threadIdx.x;
    if (e < E){
        int is64 = flags[0];
        int d = load_dst(ei, e, E, is64);
        int s = load_src(ei, e, E, is64);
        if ((unsigned)d < (unsigned)N){
            int pos = atomicAdd(&cursor[d], 1);
            if ((unsigned)pos < (unsigned)E) csr[pos] = s;
        }
    }
}

// ---------- GEMM: Y[N,128](fp32) = X[N,128] @ W[128,128]; X/W dtype per flags[1] ----------
__global__ __launch_bounds__(256) void gemm_kernel(const void* __restrict__ X, const void* __restrict__ Wv,
                                                   const int* __restrict__ flags,
                                                   float* __restrict__ Y, int N){
    __shared__ float xs[32][132];
    int tid = threadIdx.x;
    int r0 = blockIdx.x * 32;
    int isbf = flags[1];

    for (int i = tid; i < 1024; i += 256){
        int r = i >> 5, k4 = i & 31;
        float4 v = make_float4(0.f, 0.f, 0.f, 0.f);
        if (r0 + r < N){
            if (isbf){
                const __hip_bfloat162* xp = (const __hip_bfloat162*)((const bf16*)X + (size_t)(r0 + r)*128 + k4*4);
                __hip_bfloat162 p0 = xp[0], p1 = xp[1];
                v = make_float4(__bfloat162float(p0.x), __bfloat162float(p0.y),
                                __bfloat162float(p1.x), __bfloat162float(p1.y));
            } else {
                v = ((const float4*)X)[(size_t)(r0 + r)*32 + k4];
            }
        }
        *(float4*)&xs[r][k4*4] = v;
    }
    __syncthreads();

    int cp = tid & 63;
    int rg = tid >> 6;
    float acc0[8], acc1[8];
    #pragma unroll
    for (int i = 0; i < 8; i++){ acc0[i] = 0.f; acc1[i] = 0.f; }

    if (isbf){
        const bf16* W = (const bf16*)Wv;
        for (int k0 = 0; k0 < 128; k0 += 4){
            float wa0 = __bfloat162float(W[(k0+0)*128 + cp]);
            float wa1 = __bfloat162float(W[(k0+1)*128 + cp]);
            float wa2 = __bfloat162float(W[(k0+2)*128 + cp]);
            float wa3 = __bfloat162float(W[(k0+3)*128 + cp]);
            float wb0 = __bfloat162float(W[(k0+0)*128 + cp + 64]);
            float wb1 = __bfloat162float(W[(k0+1)*128 + cp + 64]);
            float wb2 = __bfloat162float(W[(k0+2)*128 + cp + 64]);
            float wb3 = __bfloat162float(W[(k0+3)*128 + cp + 64]);
            #pragma unroll
            for (int rr = 0; rr < 8; rr++){
                float4 xv = *(const float4*)&xs[rg*8 + rr][k0];
                acc0[rr] += xv.x*wa0; acc0[rr] += xv.y*wa1; acc0[rr] += xv.z*wa2; acc0[rr] += xv.w*wa3;
                acc1[rr] += xv.x*wb0; acc1[rr] += xv.y*wb1; acc1[rr] += xv.z*wb2; acc1[rr] += xv.w*wb3;
            }
        }
    } else {
        const float* W = (const float*)Wv;
        for (int k0 = 0; k0 < 128; k0 += 4){
            float wa0 = W[(k0+0)*128 + cp];
            float wa1 = W[(k0+1)*128 + cp];
            float wa2 = W[(k0+2)*128 + cp];
            float wa3 = W[(k0+3)*128 + cp];
            float wb0 = W[(k0+0)*128 + cp + 64];
            float wb1 = W[(k0+1)*128 + cp + 64];
            float wb2 = W[(k0+2)*128 + cp + 64];
            float wb3 = W[(k0+3)*128 + cp + 64];
            #pragma unroll
            for (int rr = 0; rr < 8; rr++){
                float4 xv = *(const float4*)&xs[rg*8 + rr][k0];
                acc0[rr] += xv.x*wa0; acc0[rr] += xv.y*wa1; acc0[rr] += xv.z*wa2; acc0[rr] += xv.w*wa3;
                acc1[rr] += xv.x*wb0; acc1[rr] += xv.y*wb1; acc1[rr] += xv.z*wb2; acc1[rr] += xv.w*wb3;
            }
        }
    }

    #pragma unroll
    for (int rr = 0; rr < 8; rr++){
        int r = r0 + rg*8 + rr;
        if (r < N){
            Y[(size_t)r*128 + cp]      = acc0[rr];
            Y[(size_t)r*128 + cp + 64] = acc1[rr];
        }
    }
}

// ---------- aggregation: one wave per dst row; XW fp32; H written in output dtype ----------
__global__ __launch_bounds__(256) void agg_kernel(const float* __restrict__ XW, const float* __restrict__ dinv,
                                                  const int* __restrict__ offsets, const int* __restrict__ counts,
                                                  const int* __restrict__ csr, const void* __restrict__ bias,
                                                  void* __restrict__ Hout, const int* __restrict__ flags, int N){
    int wave = threadIdx.x >> 6;
    int lane = threadIdx.x & 63;
    int n = blockIdx.x*4 + wave;
    if (n >= N) return;
    int isbf = flags[1];

    float dn = dinv[n];
    float2 v = *(const float2*)(XW + (size_t)n*128 + lane*2);
    float sw = dn*dn;
    float accx = v.x*sw, accy = v.y*sw;

    int j0 = offsets[n], cnt = counts[n];
    for (int j = j0; j < j0 + cnt; ++j){
        int s = csr[j];
        if ((unsigned)s >= (unsigned)N) continue;
        float w = dinv[s]*dn;
        float2 u = *(const float2*)(XW + (size_t)s*128 + lane*2);
        accx += u.x*w;
        accy += u.y*w;
    }
    accx = elu_f(accx + loadf(bias, lane*2,     isbf));
    accy = elu_f(accy + loadf(bias, lane*2 + 1, isbf));
    if (isbf){
        __hip_bfloat162 p;
        p.x = __float2bfloat16(accx);
        p.y = __float2bfloat16(accy);
        *(__hip_bfloat162*)((bf16*)Hout + (size_t)n*128 + lane*2) = p;
    } else {
        *(float2*)((float*)Hout + (size_t)n*128 + lane*2) = make_float2(accx, accy);
    }
}

// ---------- MLP head (only Wm2/bm2 survive the reference's reassignment bug) ----------
__global__ __launch_bounds__(256) void mlp_kernel(const void* __restrict__ dout, const void* __restrict__ Wm,
                                                  const void* __restrict__ bm, const int* __restrict__ flags, int N){
    __shared__ float ws_[1280];
    int tid = threadIdx.x;
    int isbf = flags[1];
    for (int i = tid; i < 1280; i += 256) ws_[i] = loadf(Wm, i, isbf);
    __syncthreads();

    int idx = blockIdx.x*256 + tid;
    int row = idx >> 4;
    int c   = idx & 15;
    if (row >= N || c >= 10) return;

    float acc = 0.f;
    if (isbf){
        const bf16* hr = (const bf16*)dout + (size_t)row*128;
        #pragma unroll 8
        for (int k = 0; k < 128; k++) acc += __bfloat162float(hr[k])*ws_[k*10 + c];
    } else {
        const float* hr = (const float*)dout + (size_t)row*128;
        #pragma unroll 8
        for (int k = 0; k < 128; k++) acc += hr[k]*ws_[k*10 + c];
    }
    acc += loadf(bm, c, isbf);
    float r = elu_f(acc);
    if (isbf){
        ((bf16*)dout)[(size_t)N*128 + (size_t)row*10 + c] = __float2bfloat16(r);
    } else {
        ((float*)dout)[(size_t)N*128 + (size_t)row*10 + c] = r;
    }
}

static inline char* alignup(char* p, size_t a){ return (char*)(((uintptr_t)p + a - 1) & ~(a - 1)); }

extern "C" void kernel_launch(void* const* d_in, const int* in_sizes, int n_in,
                              void* d_out, int out_size, void* d_ws, size_t ws_size,
                              hipStream_t stream){
    const void* x  = d_in[0];
    const int*  ei = (const int*)d_in[1];
    const void* W[4] = {d_in[2], d_in[4], d_in[6], d_in[8]};
    const void* B[4] = {d_in[3], d_in[5], d_in[7], d_in[9]};
    const void* Wm2 = d_in[12];
    const void* bm2 = d_in[13];

    int N = in_sizes[0] / 128;
    int E = in_sizes[1] / 2;

    // workspace: control arrays + csr + fp32 xw  (~28.8 MB)
    char* p = (char*)d_ws;
    int*   flags    = (int*)p;                     p = alignup(p + 2*sizeof(int), 256);
    float* dinv     = (float*)p;                   p = alignup(p + (size_t)N*4, 256);
    int*   counts   = (int*)p;                     p = alignup(p + (size_t)N*4, 256);
    int*   offsets  = (int*)p;                     p = alignup(p + (size_t)N*4, 256);
    int*   cursor   = (int*)p;                     p = alignup(p + (size_t)N*4, 256);
    int*   partial  = (int*)p;                     p = alignup(p + 256*4, 256);
    int*   blockoff = (int*)p;                     p = alignup(p + 256*4, 256);
    int*   csr      = (int*)p;                     p = alignup(p + (size_t)E*4, 256);
    float* xw       = (float*)p;                   p = alignup(p + (size_t)N*128*4, 256);

    int nb = (N + 255)/256;   // 196 <= 256: single-block top scan is valid

    // min words across both dtype hypotheses for x = N*128/2 (bf16 case)
    detect_kernel <<<1, 256, 0, stream>>>((const unsigned*)ei, 2*E, (const unsigned*)x, N*128/2, flags);
    hipMemsetAsync(counts, 0, (size_t)N*sizeof(int), stream);
    count_kernel  <<<(E + 255)/256, 256, 0, stream>>>(ei, flags, counts, E, N);
    dinv_kernel   <<<nb, 256, 0, stream>>>(counts, dinv, N);
    partial_kernel<<<nb, 256, 0, stream>>>(counts, partial, N);
    scanp_kernel  <<<1, 256, 0, stream>>>(partial, blockoff, nb);
    offsets_kernel<<<nb, 256, 0, stream>>>(counts, blockoff, offsets, cursor, N);
    scatter_kernel<<<(E + 255)/256, 256, 0, stream>>>(ei, flags, cursor, csr, E, N);

    // h lives in d_out's h-region (output dtype); fully rewritten every layer.
    for (int l = 0; l < 4; ++l){
        const void* Xin = (l == 0) ? x : (const void*)d_out;
        gemm_kernel<<<(N + 31)/32, 256, 0, stream>>>(Xin, W[l], flags, xw, N);
        agg_kernel <<<(N + 3)/4, 256, 0, stream>>>(xw, dinv, offsets, counts, csr, B[l], d_out, flags, N);
    }
    mlp_kernel<<<((N*16) + 255)/256, 256, 0, stream>>>(d_out, Wm2, bm2, flags, N);
}

// Round 4
// 644.591 us; speedup vs baseline: 1.1128x; 1.1128x over previous
//
#include <hip/hip_runtime.h>
#include <hip/hip_bf16.h>
#include <math.h>

typedef __hip_bfloat16 bf16;

__device__ __forceinline__ float elu_f(float x){ return x > 0.f ? x : expm1f(x); }

// ---------- dtype detection (parallel) ----------
// raw[0] = OR of sampled odd 32-bit words of edge_index (0 => int64)
// raw[1] = count of sampled x words whose low-half bf16 exponent is "normal(0,1)-like"
__global__ __launch_bounds__(256) void detect_part_kernel(const unsigned* __restrict__ ei_u, int twoE_words,
                                                          const unsigned* __restrict__ x_u, int min_xwords,
                                                          int* __restrict__ raw){
    __shared__ int sd[256];
    __shared__ int sc[256];
    int tid = threadIdx.x;
    int gid = blockIdx.x*256 + tid;     // 128 blocks * 256 = 32768 threads
    long long pairs = twoE_words/2;

    int orv = 0;
    if (gid < 16384 && pairs > 0){
        long long idx = ((long long)gid * pairs) / 16384;
        long long w = 2*idx + 1;
        if (w < twoE_words) orv = (int)ei_u[w];
    }
    int cnt = 0;
    int s = gid - 16384;
    if (s >= 0 && s < 4096){
        long long idx = ((long long)s * min_xwords) / 4096;
        if (idx < min_xwords){
            unsigned e = (x_u[idx] >> 7) & 0xFFu;
            cnt = (e >= 96u && e <= 160u) ? 1 : 0;
        }
    }
    sd[tid] = orv; sc[tid] = cnt;
    __syncthreads();
    #pragma unroll
    for (int off = 128; off > 0; off >>= 1){
        if (tid < off){ sd[tid] |= sd[tid+off]; sc[tid] += sc[tid+off]; }
        __syncthreads();
    }
    if (tid == 0){
        if (sd[0]) atomicOr(&raw[0], sd[0]);
        if (sc[0]) atomicAdd(&raw[1], sc[0]);
    }
}

// flags[0] = 1 if edge_index is int64; flags[1] = 1 if float arrays are bf16
__global__ void finalize_kernel(const int* __restrict__ raw, int* __restrict__ flags){
    flags[0] = (raw[0] == 0) ? 1 : 0;
    flags[1] = (raw[1]*2 > 4096) ? 1 : 0;
}

__device__ __forceinline__ int load_src(const int* ei, int e, int E, int is64){
    return is64 ? ei[2*e] : ei[e];
}
__device__ __forceinline__ int load_dst(const int* ei, int e, int E, int is64){
    return is64 ? ei[2*(E + e)] : ei[E + e];
}
__device__ __forceinline__ float loadf(const void* base, size_t idx, int isbf){
    return isbf ? __bfloat162float(((const bf16*)base)[idx]) : ((const float*)base)[idx];
}

// ---------- CSR build ----------
__global__ void count_kernel(const int* __restrict__ ei, const int* __restrict__ flags,
                             int* __restrict__ counts, int E, int N){
    int e = blockIdx.x*256 + threadIdx.x;
    if (e < E){
        int d = load_dst(ei, e, E, flags[0]);
        if ((unsigned)d < (unsigned)N) atomicAdd(&counts[d], 1);
    }
}

__global__ void dinv_kernel(const int* __restrict__ counts, float* __restrict__ dinv, int N){
    int n = blockIdx.x*256 + threadIdx.x;
    if (n < N){
        double d = (double)(counts[n] + 1);
        if (d < 1.0) d = 1.0;
        dinv[n] = (float)(1.0 / sqrt(d));
    }
}

__global__ void partial_kernel(const int* __restrict__ counts, int* __restrict__ partial, int N){
    __shared__ int sd[256];
    int tid = threadIdx.x;
    int i = blockIdx.x*256 + tid;
    sd[tid] = (i < N) ? counts[i] : 0;
    __syncthreads();
    #pragma unroll
    for (int off = 128; off > 0; off >>= 1){
        if (tid < off) sd[tid] += sd[tid+off];
        __syncthreads();
    }
    if (tid == 0) partial[blockIdx.x] = sd[0];
}

__global__ void scanp_kernel(const int* __restrict__ partial, int* __restrict__ blockoff, int nb){
    __shared__ int sd[256];
    int tid = threadIdx.x;
    int v = (tid < nb) ? partial[tid] : 0;
    sd[tid] = v;
    __syncthreads();
    #pragma unroll
    for (int off = 1; off < 256; off <<= 1){
        int t = (tid >= off) ? sd[tid-off] : 0;
        __syncthreads();
        sd[tid] += t;
        __syncthreads();
    }
    if (tid < nb) blockoff[tid] = sd[tid] - v;
}

__global__ void offsets_kernel(const int* __restrict__ counts, const int* __restrict__ blockoff,
                               int* __restrict__ offsets, int* __restrict__ cursor, int N){
    __shared__ int sd[256];
    int tid = threadIdx.x;
    int i = blockIdx.x*256 + tid;
    int v = (i < N) ? counts[i] : 0;
    sd[tid] = v;
    __syncthreads();
    #pragma unroll
    for (int off = 1; off < 256; off <<= 1){
        int t = (tid >= off) ? sd[tid-off] : 0;
        __syncthreads();
        sd[tid] += t;
        __syncthreads();
    }
    if (i < N){
        int o = blockoff[blockIdx.x] + sd[tid] - v;
        offsets[i] = o;
        cursor[i]  = o;
    }
}

__global__ void scatter_kernel(const int* __restrict__ ei, const int* __restrict__ flags,
                               int* __restrict__ cursor, int* __restrict__ csr, int E, int N){
    int e = blockIdx.x*256 + threadIdx.x;
    if (e < E){
        int is64 = flags[0];
        int d = load_dst(ei, e, E, is64);
        int s = load_src(ei, e, E, is64);
        if ((unsigned)d < (unsigned)N){
            int pos = atomicAdd(&cursor[d], 1);
            if ((unsigned)pos < (unsigned)E) csr[pos] = s;
        }
    }
}

// ---------- GEMM: Y[N,128](fp32) = X[N,128] @ W[128,128]; X/W dtype per flags[1] ----------
__global__ __launch_bounds__(256) void gemm_kernel(const void* __restrict__ X, const void* __restrict__ Wv,
                                                   const int* __restrict__ flags,
                                                   float* __restrict__ Y, int N){
    __shared__ float xs[32][132];
    int tid = threadIdx.x;
    int r0 = blockIdx.x * 32;
    int isbf = flags[1];

    for (int i = tid; i < 1024; i += 256){
        int r = i >> 5, k4 = i & 31;
        float4 v = make_float4(0.f, 0.f, 0.f, 0.f);
        if (r0 + r < N){
            if (isbf){
                const __hip_bfloat162* xp = (const __hip_bfloat162*)((const bf16*)X + (size_t)(r0 + r)*128 + k4*4);
                __hip_bfloat162 p0 = xp[0], p1 = xp[1];
                v = make_float4(__bfloat162float(p0.x), __bfloat162float(p0.y),
                                __bfloat162float(p1.x), __bfloat162float(p1.y));
            } else {
                v = ((const float4*)X)[(size_t)(r0 + r)*32 + k4];
            }
        }
        *(float4*)&xs[r][k4*4] = v;
    }
    __syncthreads();

    int cp = tid & 63;
    int rg = tid >> 6;
    float acc0[8], acc1[8];
    #pragma unroll
    for (int i = 0; i < 8; i++){ acc0[i] = 0.f; acc1[i] = 0.f; }

    if (isbf){
        const bf16* W = (const bf16*)Wv;
        for (int k0 = 0; k0 < 128; k0 += 4){
            float wa0 = __bfloat162float(W[(k0+0)*128 + cp]);
            float wa1 = __bfloat162float(W[(k0+1)*128 + cp]);
            float wa2 = __bfloat162float(W[(k0+2)*128 + cp]);
            float wa3 = __bfloat162float(W[(k0+3)*128 + cp]);
            float wb0 = __bfloat162float(W[(k0+0)*128 + cp + 64]);
            float wb1 = __bfloat162float(W[(k0+1)*128 + cp + 64]);
            float wb2 = __bfloat162float(W[(k0+2)*128 + cp + 64]);
            float wb3 = __bfloat162float(W[(k0+3)*128 + cp + 64]);
            #pragma unroll
            for (int rr = 0; rr < 8; rr++){
                float4 xv = *(const float4*)&xs[rg*8 + rr][k0];
                acc0[rr] += xv.x*wa0; acc0[rr] += xv.y*wa1; acc0[rr] += xv.z*wa2; acc0[rr] += xv.w*wa3;
                acc1[rr] += xv.x*wb0; acc1[rr] += xv.y*wb1; acc1[rr] += xv.z*wb2; acc1[rr] += xv.w*wb3;
            }
        }
    } else {
        const float* W = (const float*)Wv;
        for (int k0 = 0; k0 < 128; k0 += 4){
            float wa0 = W[(k0+0)*128 + cp];
            float wa1 = W[(k0+1)*128 + cp];
            float wa2 = W[(k0+2)*128 + cp];
            float wa3 = W[(k0+3)*128 + cp];
            float wb0 = W[(k0+0)*128 + cp + 64];
            float wb1 = W[(k0+1)*128 + cp + 64];
            float wb2 = W[(k0+2)*128 + cp + 64];
            float wb3 = W[(k0+3)*128 + cp + 64];
            #pragma unroll
            for (int rr = 0; rr < 8; rr++){
                float4 xv = *(const float4*)&xs[rg*8 + rr][k0];
                acc0[rr] += xv.x*wa0; acc0[rr] += xv.y*wa1; acc0[rr] += xv.z*wa2; acc0[rr] += xv.w*wa3;
                acc1[rr] += xv.x*wb0; acc1[rr] += xv.y*wb1; acc1[rr] += xv.z*wb2; acc1[rr] += xv.w*wb3;
            }
        }
    }

    #pragma unroll
    for (int rr = 0; rr < 8; rr++){
        int r = r0 + rg*8 + rr;
        if (r < N){
            Y[(size_t)r*128 + cp]      = acc0[rr];
            Y[(size_t)r*128 + cp + 64] = acc1[rr];
        }
    }
}

// ---------- aggregation: one wave per dst row; XW fp32; H written in output dtype ----------
__global__ __launch_bounds__(256) void agg_kernel(const float* __restrict__ XW, const float* __restrict__ dinv,
                                                  const int* __restrict__ offsets, const int* __restrict__ counts,
                                                  const int* __restrict__ csr, const void* __restrict__ bias,
                                                  void* __restrict__ Hout, const int* __restrict__ flags, int N){
    int wave = threadIdx.x >> 6;
    int lane = threadIdx.x & 63;
    int n = blockIdx.x*4 + wave;
    if (n >= N) return;
    int isbf = flags[1];

    float dn = dinv[n];
    float2 v = *(const float2*)(XW + (size_t)n*128 + lane*2);
    float sw = dn*dn;
    float accx = v.x*sw, accy = v.y*sw;

    int j0 = offsets[n], cnt = counts[n];
    for (int j = j0; j < j0 + cnt; ++j){
        int s = csr[j];
        if ((unsigned)s >= (unsigned)N) continue;
        float w = dinv[s]*dn;
        float2 u = *(const float2*)(XW + (size_t)s*128 + lane*2);
        accx += u.x*w;
        accy += u.y*w;
    }
    accx = elu_f(accx + loadf(bias, lane*2,     isbf));
    accy = elu_f(accy + loadf(bias, lane*2 + 1, isbf));
    if (isbf){
        __hip_bfloat162 p;
        p.x = __float2bfloat16(accx);
        p.y = __float2bfloat16(accy);
        *(__hip_bfloat162*)((bf16*)Hout + (size_t)n*128 + lane*2) = p;
    } else {
        *(float2*)((float*)Hout + (size_t)n*128 + lane*2) = make_float2(accx, accy);
    }
}

// ---------- MLP head (only Wm2/bm2 survive the reference's reassignment bug) ----------
__global__ __launch_bounds__(256) void mlp_kernel(const void* __restrict__ dout, const void* __restrict__ Wm,
                                                  const void* __restrict__ bm, const int* __restrict__ flags, int N){
    __shared__ float ws_[1280];
    int tid = threadIdx.x;
    int isbf = flags[1];
    for (int i = tid; i < 1280; i += 256) ws_[i] = loadf(Wm, i, isbf);
    __syncthreads();

    int idx = blockIdx.x*256 + tid;
    int row = idx >> 4;
    int c   = idx & 15;
    if (row >= N || c >= 10) return;

    float acc = 0.f;
    if (isbf){
        const bf16* hr = (const bf16*)dout + (size_t)row*128;
        #pragma unroll 8
        for (int k = 0; k < 128; k++) acc += __bfloat162float(hr[k])*ws_[k*10 + c];
    } else {
        const float* hr = (const float*)dout + (size_t)row*128;
        #pragma unroll 8
        for (int k = 0; k < 128; k++) acc += hr[k]*ws_[k*10 + c];
    }
    acc += loadf(bm, c, isbf);
    float r = elu_f(acc);
    if (isbf){
        ((bf16*)dout)[(size_t)N*128 + (size_t)row*10 + c] = __float2bfloat16(r);
    } else {
        ((float*)dout)[(size_t)N*128 + (size_t)row*10 + c] = r;
    }
}

static inline char* alignup(char* p, size_t a){ return (char*)(((uintptr_t)p + a - 1) & ~(a - 1)); }

extern "C" void kernel_launch(void* const* d_in, const int* in_sizes, int n_in,
                              void* d_out, int out_size, void* d_ws, size_t ws_size,
                              hipStream_t stream){
    const void* x  = d_in[0];
    const int*  ei = (const int*)d_in[1];
    const void* W[4] = {d_in[2], d_in[4], d_in[6], d_in[8]};
    const void* B[4] = {d_in[3], d_in[5], d_in[7], d_in[9]};
    const void* Wm2 = d_in[12];
    const void* bm2 = d_in[13];

    int N = in_sizes[0] / 128;
    int E = in_sizes[1] / 2;

    // workspace: control arrays + csr + fp32 xw  (~28.8 MB)
    char* p = (char*)d_ws;
    int*   flags    = (int*)p;                     // flags[0..1], raw[0..1] share one 256B slot
    int*   raw      = flags + 2;                   p = alignup(p + 4*sizeof(int), 256);
    float* dinv     = (float*)p;                   p = alignup(p + (size_t)N*4, 256);
    int*   counts   = (int*)p;                     p = alignup(p + (size_t)N*4, 256);
    int*   offsets  = (int*)p;                     p = alignup(p + (size_t)N*4, 256);
    int*   cursor   = (int*)p;                     p = alignup(p + (size_t)N*4, 256);
    int*   partial  = (int*)p;                     p = alignup(p + 256*4, 256);
    int*   blockoff = (int*)p;                     p = alignup(p + 256*4, 256);
    int*   csr      = (int*)p;                     p = alignup(p + (size_t)E*4, 256);
    float* xw       = (float*)p;                   p = alignup(p + (size_t)N*128*4, 256);

    int nb = (N + 255)/256;   // 196 <= 256: single-block top scan is valid

    hipMemsetAsync(flags, 0, 4*sizeof(int), stream);
    hipMemsetAsync(counts, 0, (size_t)N*sizeof(int), stream);
    detect_part_kernel<<<128, 256, 0, stream>>>((const unsigned*)ei, 2*E, (const unsigned*)x, N*128/2, raw);
    finalize_kernel   <<<1, 1, 0, stream>>>(raw, flags);
    count_kernel  <<<(E + 255)/256, 256, 0, stream>>>(ei, flags, counts, E, N);
    dinv_kernel   <<<nb, 256, 0, stream>>>(counts, dinv, N);
    partial_kernel<<<nb, 256, 0, stream>>>(counts, partial, N);
    scanp_kernel  <<<1, 256, 0, stream>>>(partial, blockoff, nb);
    offsets_kernel<<<nb, 256, 0, stream>>>(counts, blockoff, offsets, cursor, N);
    scatter_kernel<<<(E + 255)/256, 256, 0, stream>>>(ei, flags, cursor, csr, E, N);

    // h lives in d_out's h-region (output dtype); fully rewritten every layer.
    for (int l = 0; l < 4; ++l){
        const void* Xin = (l == 0) ? x : (const void*)d_out;
        gemm_kernel<<<(N + 31)/32, 256, 0, stream>>>(Xin, W[l], flags, xw, N);
        agg_kernel <<<(N + 3)/4, 256, 0, stream>>>(xw, dinv, offsets, counts, csr, B[l], d_out, flags, N);
    }
    mlp_kernel<<<((N*16) + 255)/256, 256, 0, stream>>>(d_out, Wm2, bm2, flags, N);
}

// Round 5
// 550.286 us; speedup vs baseline: 1.3035x; 1.1714x over previous
//
#include <hip/hip_runtime.h>
#include <hip/hip_bf16.h>
#include <math.h>

typedef __hip_bfloat16 bf16;

__device__ __forceinline__ float elu_f(float x){ return x > 0.f ? x : expm1f(x); }

// ---------- dtype detection (parallel) ----------
// raw[0] = OR of sampled odd 32-bit words of edge_index (0 => int64)
// raw[1] = count of sampled x words whose low-half bf16 exponent is "normal(0,1)-like"
__global__ __launch_bounds__(256) void detect_part_kernel(const unsigned* __restrict__ ei_u, int twoE_words,
                                                          const unsigned* __restrict__ x_u, int min_xwords,
                                                          int* __restrict__ raw){
    __shared__ int sd[256];
    __shared__ int sc[256];
    int tid = threadIdx.x;
    int gid = blockIdx.x*256 + tid;     // 128 blocks * 256 = 32768 threads
    long long pairs = twoE_words/2;

    int orv = 0;
    if (gid < 16384 && pairs > 0){
        long long idx = ((long long)gid * pairs) / 16384;
        long long w = 2*idx + 1;
        if (w < twoE_words) orv = (int)ei_u[w];
    }
    int cnt = 0;
    int s = gid - 16384;
    if (s >= 0 && s < 4096){
        long long idx = ((long long)s * min_xwords) / 4096;
        if (idx < min_xwords){
            unsigned e = (x_u[idx] >> 7) & 0xFFu;
            cnt = (e >= 96u && e <= 160u) ? 1 : 0;
        }
    }
    sd[tid] = orv; sc[tid] = cnt;
    __syncthreads();
    #pragma unroll
    for (int off = 128; off > 0; off >>= 1){
        if (tid < off){ sd[tid] |= sd[tid+off]; sc[tid] += sc[tid+off]; }
        __syncthreads();
    }
    if (tid == 0){
        if (sd[0]) atomicOr(&raw[0], sd[0]);
        if (sc[0]) atomicAdd(&raw[1], sc[0]);
    }
}

// flags[0] = 1 if edge_index is int64; flags[1] = 1 if float arrays are bf16
__global__ void finalize_kernel(const int* __restrict__ raw, int* __restrict__ flags){
    flags[0] = (raw[0] == 0) ? 1 : 0;
    flags[1] = (raw[1]*2 > 4096) ? 1 : 0;
}

__device__ __forceinline__ int load_src(const int* ei, int e, int E, int is64){
    return is64 ? ei[2*e] : ei[e];
}
__device__ __forceinline__ int load_dst(const int* ei, int e, int E, int is64){
    return is64 ? ei[2*(E + e)] : ei[E + e];
}
__device__ __forceinline__ float loadf(const void* base, size_t idx, int isbf){
    return isbf ? __bfloat162float(((const bf16*)base)[idx]) : ((const float*)base)[idx];
}

// ---------- CSR build ----------
__global__ void count_kernel(const int* __restrict__ ei, const int* __restrict__ flags,
                             int* __restrict__ counts, int E, int N){
    int e = blockIdx.x*256 + threadIdx.x;
    if (e < E){
        int d = load_dst(ei, e, E, flags[0]);
        if ((unsigned)d < (unsigned)N) atomicAdd(&counts[d], 1);
    }
}

__global__ void dinv_kernel(const int* __restrict__ counts, float* __restrict__ dinv, int N){
    int n = blockIdx.x*256 + threadIdx.x;
    if (n < N){
        double d = (double)(counts[n] + 1);
        if (d < 1.0) d = 1.0;
        dinv[n] = (float)(1.0 / sqrt(d));
    }
}

__global__ void partial_kernel(const int* __restrict__ counts, int* __restrict__ partial, int N){
    __shared__ int sd[256];
    int tid = threadIdx.x;
    int i = blockIdx.x*256 + tid;
    sd[tid] = (i < N) ? counts[i] : 0;
    __syncthreads();
    #pragma unroll
    for (int off = 128; off > 0; off >>= 1){
        if (tid < off) sd[tid] += sd[tid+off];
        __syncthreads();
    }
    if (tid == 0) partial[blockIdx.x] = sd[0];
}

__global__ void scanp_kernel(const int* __restrict__ partial, int* __restrict__ blockoff, int nb){
    __shared__ int sd[256];
    int tid = threadIdx.x;
    int v = (tid < nb) ? partial[tid] : 0;
    sd[tid] = v;
    __syncthreads();
    #pragma unroll
    for (int off = 1; off < 256; off <<= 1){
        int t = (tid >= off) ? sd[tid-off] : 0;
        __syncthreads();
        sd[tid] += t;
        __syncthreads();
    }
    if (tid < nb) blockoff[tid] = sd[tid] - v;
}

__global__ void offsets_kernel(const int* __restrict__ counts, const int* __restrict__ blockoff,
                               int* __restrict__ offsets, int* __restrict__ cursor, int N){
    __shared__ int sd[256];
    int tid = threadIdx.x;
    int i = blockIdx.x*256 + tid;
    int v = (i < N) ? counts[i] : 0;
    sd[tid] = v;
    __syncthreads();
    #pragma unroll
    for (int off = 1; off < 256; off <<= 1){
        int t = (tid >= off) ? sd[tid-off] : 0;
        __syncthreads();
        sd[tid] += t;
        __syncthreads();
    }
    if (i < N){
        int o = blockoff[blockIdx.x] + sd[tid] - v;
        offsets[i] = o;
        cursor[i]  = o;
    }
}

__global__ void scatter_kernel(const int* __restrict__ ei, const int* __restrict__ flags,
                               int* __restrict__ cursor, int* __restrict__ csr, int E, int N){
    int e = blockIdx.x*256 + threadIdx.x;
    if (e < E){
        int is64 = flags[0];
        int d = load_dst(ei, e, E, is64);
        int s = load_src(ei, e, E, is64);
        if ((unsigned)d < (unsigned)N){
            int pos = atomicAdd(&cursor[d], 1);
            if ((unsigned)pos < (unsigned)E) csr[pos] = s;
        }
    }
}

// ---------- GEMM: Y[N,128] = X[N,128] @ W[128,128]; fp32 accum.
// bf16 path: Y stored bf16, thread handles adjacent cols (2c,2c+1), packed 4B W-loads/stores.
// fp32 path: Y stored fp32, legacy (cp, cp+64) mapping.
__global__ __launch_bounds__(256) void gemm_kernel(const void* __restrict__ X, const void* __restrict__ Wv,
                                                   const int* __restrict__ flags,
                                                   void* __restrict__ Y, int N){
    __shared__ float xs[32][132];
    int tid = threadIdx.x;
    int r0 = blockIdx.x * 32;
    int isbf = flags[1];

    for (int i = tid; i < 1024; i += 256){
        int r = i >> 5, k4 = i & 31;
        float4 v = make_float4(0.f, 0.f, 0.f, 0.f);
        if (r0 + r < N){
            if (isbf){
                const __hip_bfloat162* xp = (const __hip_bfloat162*)((const bf16*)X + (size_t)(r0 + r)*128 + k4*4);
                __hip_bfloat162 p0 = xp[0], p1 = xp[1];
                v = make_float4(__bfloat162float(p0.x), __bfloat162float(p0.y),
                                __bfloat162float(p1.x), __bfloat162float(p1.y));
            } else {
                v = ((const float4*)X)[(size_t)(r0 + r)*32 + k4];
            }
        }
        *(float4*)&xs[r][k4*4] = v;
    }
    __syncthreads();

    int rg = tid >> 6;
    float acc0[8], acc1[8];
    #pragma unroll
    for (int i = 0; i < 8; i++){ acc0[i] = 0.f; acc1[i] = 0.f; }

    if (isbf){
        int c2 = tid & 63;   // cols 2*c2, 2*c2+1
        const __hip_bfloat162* W2 = (const __hip_bfloat162*)Wv;
        for (int k0 = 0; k0 < 128; k0 += 4){
            __hip_bfloat162 q0 = W2[(size_t)(k0+0)*64 + c2];
            __hip_bfloat162 q1 = W2[(size_t)(k0+1)*64 + c2];
            __hip_bfloat162 q2 = W2[(size_t)(k0+2)*64 + c2];
            __hip_bfloat162 q3 = W2[(size_t)(k0+3)*64 + c2];
            float wx0 = __bfloat162float(q0.x), wy0 = __bfloat162float(q0.y);
            float wx1 = __bfloat162float(q1.x), wy1 = __bfloat162float(q1.y);
            float wx2 = __bfloat162float(q2.x), wy2 = __bfloat162float(q2.y);
            float wx3 = __bfloat162float(q3.x), wy3 = __bfloat162float(q3.y);
            #pragma unroll
            for (int rr = 0; rr < 8; rr++){
                float4 xv = *(const float4*)&xs[rg*8 + rr][k0];
                acc0[rr] += xv.x*wx0; acc0[rr] += xv.y*wx1; acc0[rr] += xv.z*wx2; acc0[rr] += xv.w*wx3;
                acc1[rr] += xv.x*wy0; acc1[rr] += xv.y*wy1; acc1[rr] += xv.z*wy2; acc1[rr] += xv.w*wy3;
            }
        }
        #pragma unroll
        for (int rr = 0; rr < 8; rr++){
            int r = r0 + rg*8 + rr;
            if (r < N){
                __hip_bfloat162 p;
                p.x = __float2bfloat16(acc0[rr]);
                p.y = __float2bfloat16(acc1[rr]);
                ((__hip_bfloat162*)Y)[(size_t)r*64 + c2] = p;
            }
        }
    } else {
        int cp = tid & 63;   // cols cp, cp+64
        const float* W = (const float*)Wv;
        for (int k0 = 0; k0 < 128; k0 += 4){
            float wa0 = W[(k0+0)*128 + cp];
            float wa1 = W[(k0+1)*128 + cp];
            float wa2 = W[(k0+2)*128 + cp];
            float wa3 = W[(k0+3)*128 + cp];
            float wb0 = W[(k0+0)*128 + cp + 64];
            float wb1 = W[(k0+1)*128 + cp + 64];
            float wb2 = W[(k0+2)*128 + cp + 64];
            float wb3 = W[(k0+3)*128 + cp + 64];
            #pragma unroll
            for (int rr = 0; rr < 8; rr++){
                float4 xv = *(const float4*)&xs[rg*8 + rr][k0];
                acc0[rr] += xv.x*wa0; acc0[rr] += xv.y*wa1; acc0[rr] += xv.z*wa2; acc0[rr] += xv.w*wa3;
                acc1[rr] += xv.x*wb0; acc1[rr] += xv.y*wb1; acc1[rr] += xv.z*wb2; acc1[rr] += xv.w*wb3;
            }
        }
        #pragma unroll
        for (int rr = 0; rr < 8; rr++){
            int r = r0 + rg*8 + rr;
            if (r < N){
                ((float*)Y)[(size_t)r*128 + cp]      = acc0[rr];
                ((float*)Y)[(size_t)r*128 + cp + 64] = acc1[rr];
            }
        }
    }
}

// ---------- aggregation: one wave per dst row; lane-batched index/weight prefetch,
// shfl broadcast, x4 unrolled row gathers. XW dtype = flags[1]; H written in output dtype.
__global__ __launch_bounds__(256) void agg_kernel(const void* __restrict__ XW, const float* __restrict__ dinv,
                                                  const int* __restrict__ offsets, const int* __restrict__ counts,
                                                  const int* __restrict__ csr, const void* __restrict__ bias,
                                                  void* __restrict__ Hout, const int* __restrict__ flags, int N){
    int wave = threadIdx.x >> 6;
    int lane = threadIdx.x & 63;
    int n = blockIdx.x*4 + wave;
    if (n >= N) return;
    int isbf = flags[1];

    float dn = dinv[n];
    float sw = dn*dn;
    float accx, accy;
    if (isbf){
        __hip_bfloat162 v = ((const __hip_bfloat162*)XW)[(size_t)n*64 + lane];
        accx = __bfloat162float(v.x)*sw; accy = __bfloat162float(v.y)*sw;
    } else {
        float2 v = ((const float2*)XW)[(size_t)n*64 + lane];
        accx = v.x*sw; accy = v.y*sw;
    }

    int j0 = offsets[n], cnt = counts[n];
    for (int base = 0; base < cnt; base += 64){
        int m = cnt - base; if (m > 64) m = 64;
        // lane-parallel prefetch of up to 64 neighbor indices and weights (2 coalesced-ish gathers)
        int s_l = 0; float w_l = 0.f;
        if (lane < m){
            int s = csr[j0 + base + lane];
            if ((unsigned)s < (unsigned)N){ s_l = s; w_l = dinv[s]*dn; }
        }
        int j = 0;
        if (isbf){
            const __hip_bfloat162* XB = (const __hip_bfloat162*)XW;
            for (; j + 4 <= m; j += 4){
                int   s0 = __shfl(s_l, j),   s1 = __shfl(s_l, j+1), s2 = __shfl(s_l, j+2), s3 = __shfl(s_l, j+3);
                float w0 = __shfl(w_l, j),   w1 = __shfl(w_l, j+1), w2 = __shfl(w_l, j+2), w3 = __shfl(w_l, j+3);
                __hip_bfloat162 u0 = XB[(size_t)s0*64 + lane];
                __hip_bfloat162 u1 = XB[(size_t)s1*64 + lane];
                __hip_bfloat162 u2 = XB[(size_t)s2*64 + lane];
                __hip_bfloat162 u3 = XB[(size_t)s3*64 + lane];
                accx += __bfloat162float(u0.x)*w0; accy += __bfloat162float(u0.y)*w0;
                accx += __bfloat162float(u1.x)*w1; accy += __bfloat162float(u1.y)*w1;
                accx += __bfloat162float(u2.x)*w2; accy += __bfloat162float(u2.y)*w2;
                accx += __bfloat162float(u3.x)*w3; accy += __bfloat162float(u3.y)*w3;
            }
            for (; j < m; ++j){
                int   s = __shfl(s_l, j);
                float w = __shfl(w_l, j);
                __hip_bfloat162 u = XB[(size_t)s*64 + lane];
                accx += __bfloat162float(u.x)*w; accy += __bfloat162float(u.y)*w;
            }
        } else {
            const float2* XF = (const float2*)XW;
            for (; j + 4 <= m; j += 4){
                int   s0 = __shfl(s_l, j),   s1 = __shfl(s_l, j+1), s2 = __shfl(s_l, j+2), s3 = __shfl(s_l, j+3);
                float w0 = __shfl(w_l, j),   w1 = __shfl(w_l, j+1), w2 = __shfl(w_l, j+2), w3 = __shfl(w_l, j+3);
                float2 u0 = XF[(size_t)s0*64 + lane];
                float2 u1 = XF[(size_t)s1*64 + lane];
                float2 u2 = XF[(size_t)s2*64 + lane];
                float2 u3 = XF[(size_t)s3*64 + lane];
                accx += u0.x*w0; accy += u0.y*w0;
                accx += u1.x*w1; accy += u1.y*w1;
                accx += u2.x*w2; accy += u2.y*w2;
                accx += u3.x*w3; accy += u3.y*w3;
            }
            for (; j < m; ++j){
                int   s = __shfl(s_l, j);
                float w = __shfl(w_l, j);
                float2 u = XF[(size_t)s*64 + lane];
                accx += u.x*w; accy += u.y*w;
            }
        }
    }

    accx = elu_f(accx + loadf(bias, lane*2,     isbf));
    accy = elu_f(accy + loadf(bias, lane*2 + 1, isbf));
    if (isbf){
        __hip_bfloat162 p;
        p.x = __float2bfloat16(accx);
        p.y = __float2bfloat16(accy);
        *(__hip_bfloat162*)((bf16*)Hout + (size_t)n*128 + lane*2) = p;
    } else {
        *(float2*)((float*)Hout + (size_t)n*128 + lane*2) = make_float2(accx, accy);
    }
}

// ---------- MLP head (only Wm2/bm2 survive the reference's reassignment bug) ----------
__global__ __launch_bounds__(256) void mlp_kernel(const void* __restrict__ dout, const void* __restrict__ Wm,
                                                  const void* __restrict__ bm, const int* __restrict__ flags, int N){
    __shared__ float ws_[1280];
    int tid = threadIdx.x;
    int isbf = flags[1];
    for (int i = tid; i < 1280; i += 256) ws_[i] = loadf(Wm, i, isbf);
    __syncthreads();

    int idx = blockIdx.x*256 + tid;
    int row = idx >> 4;
    int c   = idx & 15;
    if (row >= N || c >= 10) return;

    float acc = 0.f;
    if (isbf){
        const bf16* hr = (const bf16*)dout + (size_t)row*128;
        #pragma unroll 8
        for (int k = 0; k < 128; k++) acc += __bfloat162float(hr[k])*ws_[k*10 + c];
    } else {
        const float* hr = (const float*)dout + (size_t)row*128;
        #pragma unroll 8
        for (int k = 0; k < 128; k++) acc += hr[k]*ws_[k*10 + c];
    }
    acc += loadf(bm, c, isbf);
    float r = elu_f(acc);
    if (isbf){
        ((bf16*)dout)[(size_t)N*128 + (size_t)row*10 + c] = __float2bfloat16(r);
    } else {
        ((float*)dout)[(size_t)N*128 + (size_t)row*10 + c] = r;
    }
}

static inline char* alignup(char* p, size_t a){ return (char*)(((uintptr_t)p + a - 1) & ~(a - 1)); }

extern "C" void kernel_launch(void* const* d_in, const int* in_sizes, int n_in,
                              void* d_out, int out_size, void* d_ws, size_t ws_size,
                              hipStream_t stream){
    const void* x  = d_in[0];
    const int*  ei = (const int*)d_in[1];
    const void* W[4] = {d_in[2], d_in[4], d_in[6], d_in[8]};
    const void* B[4] = {d_in[3], d_in[5], d_in[7], d_in[9]};
    const void* Wm2 = d_in[12];
    const void* bm2 = d_in[13];

    int N = in_sizes[0] / 128;
    int E = in_sizes[1] / 2;

    // workspace: control arrays + csr + xw (sized for fp32 worst case; bf16 path uses half)
    char* p = (char*)d_ws;
    int*   flags    = (int*)p;                     // flags[0..1], raw[0..1] share one 256B slot
    int*   raw      = flags + 2;                   p = alignup(p + 4*sizeof(int), 256);
    float* dinv     = (float*)p;                   p = alignup(p + (size_t)N*4, 256);
    int*   counts   = (int*)p;                     p = alignup(p + (size_t)N*4, 256);
    int*   offsets  = (int*)p;                     p = alignup(p + (size_t)N*4, 256);
    int*   cursor   = (int*)p;                     p = alignup(p + (size_t)N*4, 256);
    int*   partial  = (int*)p;                     p = alignup(p + 256*4, 256);
    int*   blockoff = (int*)p;                     p = alignup(p + 256*4, 256);
    int*   csr      = (int*)p;                     p = alignup(p + (size_t)E*4, 256);
    void*  xw       = (void*)p;                    p = alignup(p + (size_t)N*128*4, 256);

    int nb = (N + 255)/256;   // 196 <= 256: single-block top scan is valid

    hipMemsetAsync(flags, 0, 4*sizeof(int), stream);
    hipMemsetAsync(counts, 0, (size_t)N*sizeof(int), stream);
    detect_part_kernel<<<128, 256, 0, stream>>>((const unsigned*)ei, 2*E, (const unsigned*)x, N*128/2, raw);
    finalize_kernel   <<<1, 1, 0, stream>>>(raw, flags);
    count_kernel  <<<(E + 255)/256, 256, 0, stream>>>(ei, flags, counts, E, N);
    dinv_kernel   <<<nb, 256, 0, stream>>>(counts, dinv, N);
    partial_kernel<<<nb, 256, 0, stream>>>(counts, partial, N);
    scanp_kernel  <<<1, 256, 0, stream>>>(partial, blockoff, nb);
    offsets_kernel<<<nb, 256, 0, stream>>>(counts, blockoff, offsets, cursor, N);
    scatter_kernel<<<(E + 255)/256, 256, 0, stream>>>(ei, flags, cursor, csr, E, N);

    // h lives in d_out's h-region (output dtype); fully rewritten every layer.
    for (int l = 0; l < 4; ++l){
        const void* Xin = (l == 0) ? x : (const void*)d_out;
        gemm_kernel<<<(N + 31)/32, 256, 0, stream>>>(Xin, W[l], flags, xw, N);
        agg_kernel <<<(N + 3)/4, 256, 0, stream>>>(xw, dinv, offsets, counts, csr, B[l], d_out, flags, N);
    }
    mlp_kernel<<<((N*16) + 255)/256, 256, 0, stream>>>(d_out, Wm2, bm2, flags, N);
}